// Round 12
// baseline (226.395 us; speedup 1.0000x reference)
//
#include <hip/hip_runtime.h>

#define BATCH 4
#define NPTS 8192
#define DIM 128
#define TOTAL_ROWS (BATCH * NPTS)   // 32768
#define SLICES 8                    // m-slices per batch
#define SLICE_W 1024                // cols per slice
#define ITERS 64                    // 16-col tiles per slice
#define TILES_PER_B 512             // NPTS/16
#define TILE_B 2048                 // bytes per packed fp8 16-col tile

typedef __attribute__((ext_vector_type(8))) int   i32x8;
typedef __attribute__((ext_vector_type(4))) float f32x4;

// monotonic encoding of float for unsigned atomicMin (handles negatives)
__device__ __forceinline__ unsigned encf(float f) {
  unsigned b = __float_as_uint(f);
  return (b & 0x80000000u) ? ~b : (b | 0x80000000u);
}
__device__ __forceinline__ float decf(unsigned u) {
  unsigned b = (u & 0x80000000u) ? (u ^ 0x80000000u) : ~u;
  return __uint_as_float(b);
}

// pack 8 floats -> 8 fp8(e4m3) bytes in 2 dwords
__device__ __forceinline__ void pk8(const float4& x, const float4& y,
                                    unsigned& lo, unsigned& hi) {
  lo = __builtin_amdgcn_cvt_pk_fp8_f32(x.x, x.y, 0, 0);
  lo = __builtin_amdgcn_cvt_pk_fp8_f32(x.z, x.w, lo, 1);
  hi = __builtin_amdgcn_cvt_pk_fp8_f32(y.x, y.y, 0, 0);
  hi = __builtin_amdgcn_cvt_pk_fp8_f32(y.z, y.w, hi, 1);
}

// ---- pack f_ into fp8 MFMA-fragment order + row norms gn2 ----
__global__ void pack_b_kernel(const float* __restrict__ in,
                              unsigned char* __restrict__ pk,
                              float* __restrict__ gn2) {
  __shared__ float sred[16][17];
  int tl  = threadIdx.x;               // 0..255
  int fl  = tl >> 2;                   // fragment lane 0..63
  int p   = tl & 3;                    // 8-byte group within lane's 32
  int col = fl & 15, kch = fl >> 4;
  int tile = blockIdx.x;               // b*512 + mtg
  int b = tile >> 9, mtg = tile & 511;
  const float* src = in + (size_t)(b * NPTS + mtg * 16 + col) * DIM + kch * 32 + p * 8;
  float4 x = ((const float4*)src)[0], y = ((const float4*)src)[1];
  unsigned lo, hi;
  pk8(x, y, lo, hi);
  *(uint2*)(pk + (size_t)tile * TILE_B + (p >> 1) * 1024 + fl * 16 + (p & 1) * 8)
      = make_uint2(lo, hi);
  float s = 0.f;
  s = fmaf(x.x, x.x, s); s = fmaf(x.y, x.y, s);
  s = fmaf(x.z, x.z, s); s = fmaf(x.w, x.w, s);
  s = fmaf(y.x, y.x, s); s = fmaf(y.y, y.y, s);
  s = fmaf(y.z, y.z, s); s = fmaf(y.w, y.w, s);
  sred[col][kch * 4 + p] = s;
  __syncthreads();
  if (tl < 16) {
    float t = 0.f;
    #pragma unroll
    for (int j = 0; j < 16; ++j) t += sred[tl][j];
    gn2[tile * 16 + tl] = t;
  }
}

// ---- main: per wave, 64 f-rows (A in fp8 regs) x 1024-col slice ----
// fp8 K=128 MFMA, C-operand seeding, deferred gn2 on col side, 4-deep pipeline
__global__ __launch_bounds__(256, 4)
void chamfer_mfma_kernel(const float* __restrict__ f,
                         const unsigned char* __restrict__ pk,
                         const float* __restrict__ gn2,
                         unsigned int* __restrict__ rowmin,
                         unsigned int* __restrict__ colmin) {
  const int lane = threadIdx.x & 63;
  const int l15  = lane & 15;
  const int q    = lane >> 4;                       // 0..3
  const int widx = threadIdx.x >> 6;                // 0..3

  // XCD-aware: 4 (b,slice) combos per XCD, 32 row-groups each
  const int bid   = blockIdx.x;                     // 0..1023
  const int combo = (bid & 7) * 4 + ((bid >> 3) & 3);  // 0..31
  const int b     = combo >> 3;
  const int slice = combo & 7;
  const int rgrp  = bid >> 5;                       // 0..31
  const int r0    = rgrp * 256 + widx * 64;
  const int bN    = b * NPTS;
  const int tile0 = b * TILES_PER_B + slice * ITERS;

  // block-level column-max accumulator of raw acc0 (= -dis/2 - gn2/2 deferred)
  // stores encf(-2*cmax); gn2 added at merge
  __shared__ unsigned cl[SLICE_W];
  #pragma unroll
  for (int k = 0; k < SLICE_W / 256; ++k)
    cl[threadIdx.x + k * 256] = 0xFFFFFFFFu;
  __syncthreads();

  // ---- A fragments (4 tiles, fp8, K=128) + C-seeds h = -fn2/2 ----
  i32x8 af[4];
  f32x4 h[4];
  const float* fb = f + (size_t)bN * DIM;
  #pragma unroll
  for (int t = 0; t < 4; ++t) {
    const float* frow = fb + (size_t)(r0 + t * 16 + l15) * DIM + q * 32;
    float s = 0.f;
    i32x8 v;
    #pragma unroll
    for (int d8 = 0; d8 < 4; ++d8) {
      float4 x = ((const float4*)frow)[2 * d8];
      float4 y = ((const float4*)frow)[2 * d8 + 1];
      unsigned lo, hi;
      pk8(x, y, lo, hi);
      v[2 * d8] = (int)lo; v[2 * d8 + 1] = (int)hi;
      s = fmaf(x.x, x.x, s); s = fmaf(x.y, x.y, s);
      s = fmaf(x.z, x.z, s); s = fmaf(x.w, x.w, s);
      s = fmaf(y.x, y.x, s); s = fmaf(y.y, y.y, s);
      s = fmaf(y.z, y.z, s); s = fmaf(y.w, y.w, s);
    }
    af[t] = v;
    s += __shfl_xor(s, 16); s += __shfl_xor(s, 32);   // lane holds fn2 of row (l&15)
    #pragma unroll
    for (int i = 0; i < 4; ++i) h[t][i] = -0.5f * __shfl(s, (q << 2) + i);
  }

  float rowmax[4][4];
  #pragma unroll
  for (int t = 0; t < 4; ++t)
    #pragma unroll
    for (int i = 0; i < 4; ++i) rowmax[t][i] = -3.4e38f;

  // packed fragment base for this wave's lane
  const unsigned char* pkw = pk + (size_t)tile0 * TILE_B + lane * 16;
  const float*         gnb = gn2 + bN + slice * SLICE_W;

  auto loadB = [&](int mt, i32x8& bf, float& gv) {
    const unsigned char* base = pkw + (size_t)mt * TILE_B;
    uint4 u0 = *(const uint4*)base;
    uint4 u1 = *(const uint4*)(base + 1024);
    bf[0] = (int)u0.x; bf[1] = (int)u0.y; bf[2] = (int)u0.z; bf[3] = (int)u0.w;
    bf[4] = (int)u1.x; bf[5] = (int)u1.y; bf[6] = (int)u1.z; bf[7] = (int)u1.w;
    gv = gnb[mt * 16 + l15];
  };

  auto compute = [&](const i32x8& bf, float gv, int mt) {
    // C-operand seeding: acc0 = dot - fn2[r]/2  (no per-iter seed VALU)
    f32x4 acc[4];
    #pragma unroll
    for (int t = 0; t < 4; ++t)
      acc[t] = __builtin_amdgcn_mfma_scale_f32_16x16x128_f8f6f4(
          af[t], bf, h[t], 0, 0, 0, 0x7f7f7f7f, 0, 0x7f7f7f7f);

    // row side: rowmax tracks max(acc0 - gn2[c]/2) = -dis/2
    const float g2 = -0.5f * gv;
    #pragma unroll
    for (int t = 0; t < 4; ++t)
      #pragma unroll
      for (int i = 0; i < 4; ++i)
        rowmax[t][i] = fmaxf(rowmax[t][i], acc[t][i] + g2);

    // col side: cmax over the 16 raw acc0 (max3-fused tree: 8 ops)
    float m0 = fmaxf(fmaxf(acc[0][0], acc[0][1]), acc[0][2]);
    float m1 = fmaxf(fmaxf(acc[0][3], acc[1][0]), acc[1][1]);
    float m2 = fmaxf(fmaxf(acc[1][2], acc[1][3]), acc[2][0]);
    float m3 = fmaxf(fmaxf(acc[2][1], acc[2][2]), acc[2][3]);
    float m4 = fmaxf(fmaxf(acc[3][0], acc[3][1]), acc[3][2]);
    float n0 = fmaxf(fmaxf(m0, m1), m2);
    float n1 = fmaxf(fmaxf(m3, m4), acc[3][3]);
    float cmax = fmaxf(n0, n1);
    // fire-and-forget LDS atomic (4-way same-address per col); gn2 deferred
    atomicMin(&cl[mt * 16 + l15], encf(-2.f * cmax));
  };

  // 4-deep pipeline, named buffers, compute-then-reload rotation
  i32x8 b0, b1, b2, b3;
  float g0, g1, g2v, g3;
  loadB(0, b0, g0); loadB(1, b1, g1); loadB(2, b2, g2v); loadB(3, b3, g3);
  for (int mt = 0; mt < ITERS; mt += 4) {
    compute(b0, g0, mt);      loadB((mt + 4) & (ITERS - 1), b0, g0);
    compute(b1, g1, mt + 1);  loadB((mt + 5) & (ITERS - 1), b1, g1);
    compute(b2, g2v, mt + 2); loadB((mt + 6) & (ITERS - 1), b2, g2v);
    compute(b3, g3, mt + 3);  loadB((mt + 7) & (ITERS - 1), b3, g3);
  }

  // finalize row mins: reduce MAX over the 16 column-lanes, dis = -2*max
  #pragma unroll
  for (int t = 0; t < 4; ++t)
    #pragma unroll
    for (int i = 0; i < 4; ++i) {
      float v = rowmax[t][i];
      v = fmaxf(v, __shfl_xor(v, 1));
      v = fmaxf(v, __shfl_xor(v, 2));
      v = fmaxf(v, __shfl_xor(v, 4));
      v = fmaxf(v, __shfl_xor(v, 8));
      if (l15 == 0)
        atomicMin(&rowmin[bN + r0 + t * 16 + q * 4 + i], encf(-2.f * v));
    }

  // merge block col maxes into global: dis = decoded + gn2[col]
  __syncthreads();
  #pragma unroll
  for (int k = 0; k < SLICE_W / 256; ++k) {
    int c = threadIdx.x + k * 256;
    float d = decf(cl[c]) + gnb[c];
    atomicMin(&colmin[bN + slice * SLICE_W + c], encf(d));
  }
}

// ---- reduction stage 1: 128 blocks x 256 thr ----
__global__ void reduce1_kernel(const unsigned int* __restrict__ rowmin,
                               const unsigned int* __restrict__ colmin,
                               float* __restrict__ partial) {
  __shared__ float sbuf[4];
  int i = blockIdx.x * 256 + threadIdx.x;
  float s = decf(rowmin[i]) + decf(colmin[i]);
  #pragma unroll
  for (int o = 32; o >= 1; o >>= 1) s += __shfl_xor(s, o);
  if ((threadIdx.x & 63) == 0) sbuf[threadIdx.x >> 6] = s;
  __syncthreads();
  if (threadIdx.x == 0)
    partial[blockIdx.x] = sbuf[0] + sbuf[1] + sbuf[2] + sbuf[3];
}

// ---- reduction stage 2: 1 block, 64 thr ----
__global__ void reduce2_kernel(const float* __restrict__ partial,
                               float* __restrict__ out) {
  float s = partial[threadIdx.x] + partial[threadIdx.x + 64];
  #pragma unroll
  for (int o = 32; o >= 1; o >>= 1) s += __shfl_xor(s, o);
  if (threadIdx.x == 0) out[0] = s / (float)TOTAL_ROWS;
}

extern "C" void kernel_launch(void* const* d_in, const int* in_sizes, int n_in,
                              void* d_out, int out_size, void* d_ws, size_t ws_size,
                              hipStream_t stream) {
  (void)in_sizes; (void)n_in; (void)out_size; (void)ws_size;
  const float* f  = (const float*)d_in[0];
  const float* f_ = (const float*)d_in[1];

  char* ws = (char*)d_ws;
  unsigned char* pk = (unsigned char*)ws;                          // 4 MiB packed fp8 f_
  float* gn2 = (float*)(ws + 8u * 1024u * 1024u);                  // 128 KiB
  unsigned int* rowmin = (unsigned int*)(gn2 + TOTAL_ROWS);        // 128 KiB
  unsigned int* colmin = rowmin + TOTAL_ROWS;                      // 128 KiB
  float* partial = (float*)(colmin + TOTAL_ROWS);                  // 512 B

  pack_b_kernel<<<2048, 256, 0, stream>>>(f_, pk, gn2);
  hipMemsetAsync(rowmin, 0xFF, (size_t)TOTAL_ROWS * 4, stream);
  hipMemsetAsync(colmin, 0xFF, (size_t)TOTAL_ROWS * 4, stream);
  chamfer_mfma_kernel<<<1024, 256, 0, stream>>>(f, pk, gn2, rowmin, colmin);
  reduce1_kernel<<<128, 256, 0, stream>>>(rowmin, colmin, partial);
  reduce2_kernel<<<1, 64, 0, stream>>>(partial, (float*)d_out);
}

// Round 13
// 72.880 us; speedup vs baseline: 3.1064x; 3.1064x over previous
//
#include <hip/hip_runtime.h>

#define BATCH 4
#define NPTS 8192
#define DIM 128
#define TOTAL_ROWS (BATCH * NPTS)   // 32768
#define SLICES 8                    // m-slices per batch
#define SLICE_W 1024                // cols per slice
#define ITERS 64                    // 16-col tiles per slice
#define TILES_PER_B 512             // NPTS/16
#define TILE_B 2048                 // bytes per packed fp8 16-col tile

typedef __attribute__((ext_vector_type(8))) int   i32x8;
typedef __attribute__((ext_vector_type(4))) float f32x4;

// monotonic encoding of float for unsigned atomicMin (handles negatives)
__device__ __forceinline__ unsigned encf(float f) {
  unsigned b = __float_as_uint(f);
  return (b & 0x80000000u) ? ~b : (b | 0x80000000u);
}
__device__ __forceinline__ float decf(unsigned u) {
  unsigned b = (u & 0x80000000u) ? (u ^ 0x80000000u) : ~u;
  return __uint_as_float(b);
}

// pack 8 floats -> 8 fp8(e4m3) bytes in 2 dwords
__device__ __forceinline__ void pk8(const float4& x, const float4& y,
                                    unsigned& lo, unsigned& hi) {
  lo = __builtin_amdgcn_cvt_pk_fp8_f32(x.x, x.y, 0, 0);
  lo = __builtin_amdgcn_cvt_pk_fp8_f32(x.z, x.w, lo, 1);
  hi = __builtin_amdgcn_cvt_pk_fp8_f32(y.x, y.y, 0, 0);
  hi = __builtin_amdgcn_cvt_pk_fp8_f32(y.z, y.w, hi, 1);
}

// ---- pack f_ into fp8 MFMA-fragment order + row norms gn2 ----
__global__ void pack_b_kernel(const float* __restrict__ in,
                              unsigned char* __restrict__ pk,
                              float* __restrict__ gn2) {
  __shared__ float sred[16][17];
  int tl  = threadIdx.x;               // 0..255
  int fl  = tl >> 2;                   // fragment lane 0..63
  int p   = tl & 3;                    // 8-byte group within lane's 32
  int col = fl & 15, kch = fl >> 4;
  int tile = blockIdx.x;               // b*512 + mtg
  int b = tile >> 9, mtg = tile & 511;
  const float* src = in + (size_t)(b * NPTS + mtg * 16 + col) * DIM + kch * 32 + p * 8;
  float4 x = ((const float4*)src)[0], y = ((const float4*)src)[1];
  unsigned lo, hi;
  pk8(x, y, lo, hi);
  *(uint2*)(pk + (size_t)tile * TILE_B + (p >> 1) * 1024 + fl * 16 + (p & 1) * 8)
      = make_uint2(lo, hi);
  float s = 0.f;
  s = fmaf(x.x, x.x, s); s = fmaf(x.y, x.y, s);
  s = fmaf(x.z, x.z, s); s = fmaf(x.w, x.w, s);
  s = fmaf(y.x, y.x, s); s = fmaf(y.y, y.y, s);
  s = fmaf(y.z, y.z, s); s = fmaf(y.w, y.w, s);
  sred[col][kch * 4 + p] = s;
  __syncthreads();
  if (tl < 16) {
    float t = 0.f;
    #pragma unroll
    for (int j = 0; j < 16; ++j) t += sred[tl][j];
    gn2[tile * 16 + tl] = t;
  }
}

// ---- main: per wave, 64 f-rows (A in fp8 regs) x 1024-col slice ----
// fp8 K=128 MFMA, C-operand seeding, deferred gn2 on col side, 4-deep pipeline
// LB(256,3): 170-reg budget fits ~128 demand -> NO spill (R12's failure mode)
__global__ __launch_bounds__(256, 3)
void chamfer_mfma_kernel(const float* __restrict__ f,
                         const unsigned char* __restrict__ pk,
                         const float* __restrict__ gn2,
                         unsigned int* __restrict__ rowmin,
                         unsigned int* __restrict__ colmin) {
  const int lane = threadIdx.x & 63;
  const int l15  = lane & 15;
  const int q    = lane >> 4;                       // 0..3
  const int widx = threadIdx.x >> 6;                // 0..3

  // XCD-aware: 4 (b,slice) combos per XCD, 32 row-groups each
  const int bid   = blockIdx.x;                     // 0..1023
  const int combo = (bid & 7) * 4 + ((bid >> 3) & 3);  // 0..31
  const int b     = combo >> 3;
  const int slice = combo & 7;
  const int rgrp  = bid >> 5;                       // 0..31
  const int r0    = rgrp * 256 + widx * 64;
  const int bN    = b * NPTS;
  const int tile0 = b * TILES_PER_B + slice * ITERS;

  // block-level column-max accumulator of raw acc0; gn2 added at merge
  __shared__ unsigned cl[SLICE_W];
  #pragma unroll
  for (int k = 0; k < SLICE_W / 256; ++k)
    cl[threadIdx.x + k * 256] = 0xFFFFFFFFu;
  __syncthreads();

  // ---- A fragments (4 tiles, fp8, K=128) + C-seeds h = -fn2/2 ----
  i32x8 af[4];
  f32x4 h[4];
  const float* fb = f + (size_t)bN * DIM;
  #pragma unroll
  for (int t = 0; t < 4; ++t) {
    const float* frow = fb + (size_t)(r0 + t * 16 + l15) * DIM + q * 32;
    float s = 0.f;
    i32x8 v;
    #pragma unroll
    for (int d8 = 0; d8 < 4; ++d8) {
      float4 x = ((const float4*)frow)[2 * d8];
      float4 y = ((const float4*)frow)[2 * d8 + 1];
      unsigned lo, hi;
      pk8(x, y, lo, hi);
      v[2 * d8] = (int)lo; v[2 * d8 + 1] = (int)hi;
      s = fmaf(x.x, x.x, s); s = fmaf(x.y, x.y, s);
      s = fmaf(x.z, x.z, s); s = fmaf(x.w, x.w, s);
      s = fmaf(y.x, y.x, s); s = fmaf(y.y, y.y, s);
      s = fmaf(y.z, y.z, s); s = fmaf(y.w, y.w, s);
    }
    af[t] = v;
    s += __shfl_xor(s, 16); s += __shfl_xor(s, 32);   // lane holds fn2 of row (l&15)
    #pragma unroll
    for (int i = 0; i < 4; ++i) h[t][i] = -0.5f * __shfl(s, (q << 2) + i);
  }

  float rowmax[4][4];
  #pragma unroll
  for (int t = 0; t < 4; ++t)
    #pragma unroll
    for (int i = 0; i < 4; ++i) rowmax[t][i] = -3.4e38f;

  // packed fragment base for this wave's lane
  const unsigned char* pkw = pk + (size_t)tile0 * TILE_B + lane * 16;
  const float*         gnb = gn2 + bN + slice * SLICE_W;

  auto loadB = [&](int mt, i32x8& bf, float& gv) {
    const unsigned char* base = pkw + (size_t)mt * TILE_B;
    uint4 u0 = *(const uint4*)base;
    uint4 u1 = *(const uint4*)(base + 1024);
    bf[0] = (int)u0.x; bf[1] = (int)u0.y; bf[2] = (int)u0.z; bf[3] = (int)u0.w;
    bf[4] = (int)u1.x; bf[5] = (int)u1.y; bf[6] = (int)u1.z; bf[7] = (int)u1.w;
    gv = gnb[mt * 16 + l15];
  };

  auto compute = [&](const i32x8& bf, float gv, int mt) {
    // C-operand seeding: acc0 = dot - fn2[r]/2  (no per-iter seed VALU)
    f32x4 acc[4];
    #pragma unroll
    for (int t = 0; t < 4; ++t)
      acc[t] = __builtin_amdgcn_mfma_scale_f32_16x16x128_f8f6f4(
          af[t], bf, h[t], 0, 0, 0, 0x7f7f7f7f, 0, 0x7f7f7f7f);

    // row side: rowmax tracks max(acc0 - gn2[c]/2) = -dis/2
    const float g2 = -0.5f * gv;
    #pragma unroll
    for (int t = 0; t < 4; ++t)
      #pragma unroll
      for (int i = 0; i < 4; ++i)
        rowmax[t][i] = fmaxf(rowmax[t][i], acc[t][i] + g2);

    // col side: cmax over the 16 raw acc0 (max3-fused tree: 8 ops)
    float m0 = fmaxf(fmaxf(acc[0][0], acc[0][1]), acc[0][2]);
    float m1 = fmaxf(fmaxf(acc[0][3], acc[1][0]), acc[1][1]);
    float m2 = fmaxf(fmaxf(acc[1][2], acc[1][3]), acc[2][0]);
    float m3 = fmaxf(fmaxf(acc[2][1], acc[2][2]), acc[2][3]);
    float m4 = fmaxf(fmaxf(acc[3][0], acc[3][1]), acc[3][2]);
    float n0 = fmaxf(fmaxf(m0, m1), m2);
    float n1 = fmaxf(fmaxf(m3, m4), acc[3][3]);
    float cmax = fmaxf(n0, n1);
    // fire-and-forget LDS atomic (4-way same-address per col); gn2 deferred
    atomicMin(&cl[mt * 16 + l15], encf(-2.f * cmax));
  };

  // 4-deep pipeline, named buffers, compute-then-reload rotation (distance 3)
  i32x8 b0, b1, b2, b3;
  float g0, g1, g2v, g3;
  loadB(0, b0, g0); loadB(1, b1, g1); loadB(2, b2, g2v); loadB(3, b3, g3);
  for (int mt = 0; mt < ITERS; mt += 4) {
    compute(b0, g0, mt);      loadB((mt + 4) & (ITERS - 1), b0, g0);
    compute(b1, g1, mt + 1);  loadB((mt + 5) & (ITERS - 1), b1, g1);
    compute(b2, g2v, mt + 2); loadB((mt + 6) & (ITERS - 1), b2, g2v);
    compute(b3, g3, mt + 3);  loadB((mt + 7) & (ITERS - 1), b3, g3);
  }

  // finalize row mins: reduce MAX over the 16 column-lanes, dis = -2*max
  #pragma unroll
  for (int t = 0; t < 4; ++t)
    #pragma unroll
    for (int i = 0; i < 4; ++i) {
      float v = rowmax[t][i];
      v = fmaxf(v, __shfl_xor(v, 1));
      v = fmaxf(v, __shfl_xor(v, 2));
      v = fmaxf(v, __shfl_xor(v, 4));
      v = fmaxf(v, __shfl_xor(v, 8));
      if (l15 == 0)
        atomicMin(&rowmin[bN + r0 + t * 16 + q * 4 + i], encf(-2.f * v));
    }

  // merge block col maxes into global: dis = decoded + gn2[col]
  __syncthreads();
  #pragma unroll
  for (int k = 0; k < SLICE_W / 256; ++k) {
    int c = threadIdx.x + k * 256;
    float d = decf(cl[c]) + gnb[c];
    atomicMin(&colmin[bN + slice * SLICE_W + c], encf(d));
  }
}

// ---- reduction stage 1: 128 blocks x 256 thr ----
__global__ void reduce1_kernel(const unsigned int* __restrict__ rowmin,
                               const unsigned int* __restrict__ colmin,
                               float* __restrict__ partial) {
  __shared__ float sbuf[4];
  int i = blockIdx.x * 256 + threadIdx.x;
  float s = decf(rowmin[i]) + decf(colmin[i]);
  #pragma unroll
  for (int o = 32; o >= 1; o >>= 1) s += __shfl_xor(s, o);
  if ((threadIdx.x & 63) == 0) sbuf[threadIdx.x >> 6] = s;
  __syncthreads();
  if (threadIdx.x == 0)
    partial[blockIdx.x] = sbuf[0] + sbuf[1] + sbuf[2] + sbuf[3];
}

// ---- reduction stage 2: 1 block, 64 thr ----
__global__ void reduce2_kernel(const float* __restrict__ partial,
                               float* __restrict__ out) {
  float s = partial[threadIdx.x] + partial[threadIdx.x + 64];
  #pragma unroll
  for (int o = 32; o >= 1; o >>= 1) s += __shfl_xor(s, o);
  if (threadIdx.x == 0) out[0] = s / (float)TOTAL_ROWS;
}

extern "C" void kernel_launch(void* const* d_in, const int* in_sizes, int n_in,
                              void* d_out, int out_size, void* d_ws, size_t ws_size,
                              hipStream_t stream) {
  (void)in_sizes; (void)n_in; (void)out_size; (void)ws_size;
  const float* f  = (const float*)d_in[0];
  const float* f_ = (const float*)d_in[1];

  char* ws = (char*)d_ws;
  unsigned char* pk = (unsigned char*)ws;                          // 4 MiB packed fp8 f_
  float* gn2 = (float*)(ws + 8u * 1024u * 1024u);                  // 128 KiB
  unsigned int* rowmin = (unsigned int*)(gn2 + TOTAL_ROWS);        // 128 KiB
  unsigned int* colmin = rowmin + TOTAL_ROWS;                      // 128 KiB
  float* partial = (float*)(colmin + TOTAL_ROWS);                  // 512 B

  pack_b_kernel<<<2048, 256, 0, stream>>>(f_, pk, gn2);
  hipMemsetAsync(rowmin, 0xFF, (size_t)TOTAL_ROWS * 4, stream);
  hipMemsetAsync(colmin, 0xFF, (size_t)TOTAL_ROWS * 4, stream);
  chamfer_mfma_kernel<<<1024, 256, 0, stream>>>(f, pk, gn2, rowmin, colmin);
  reduce1_kernel<<<128, 256, 0, stream>>>(rowmin, colmin, partial);
  reduce2_kernel<<<1, 64, 0, stream>>>(partial, (float*)d_out);
}